// Round 16
// baseline (330.399 us; speedup 1.0000x reference)
//
#include <hip/hip_runtime.h>

// LSTMModel: B=4096, T=512, IN=2, H=12, OUT=2, fp32.
// r16: CHAIN-CUT. One elem/wave, 4 waves/SIMD (r10 config), un-merged layers.
// h0 broadcast (critical path) via 12 ds_bpermute register-crossbar ops --
// no LDS store->load round-trip (~240 cyc -> ~50). h1 broadcast (one full
// step of slack) stays on the cheap LDS write+read, latency fully hidden.
// L1's h1-part dot chains are placed between h0v and the bpermute consumers
// to absorb bpermute latency. pk-f2 dots (plain C++ ext-vector, r10-style),
// DPP quad gathers, kmul-folded activations.

namespace {
constexpr int H = 12;
constexpr int T = 512;
constexpr float LOG2E = 1.4426950408889634f;

typedef float f2 __attribute__((ext_vector_type(2)));

__device__ __forceinline__ f2 fma2(f2 a, f2 b, f2 c) {
    return __builtin_elementwise_fma(a, b, c);
}
__device__ __forceinline__ float exp2_(float x) {
    float r; asm("v_exp_f32 %0, %1" : "=v"(r) : "v"(x)); return r;
}
__device__ __forceinline__ float rcp_(float x) { return __builtin_amdgcn_rcpf(x); }
__device__ __forceinline__ void memfence_() { asm volatile("" ::: "memory"); }
__device__ __forceinline__ float bperm_(int addr, float v) {
    return __int_as_float(__builtin_amdgcn_ds_bpermute(addr, __float_as_int(v)));
}

template <int CTRL>
__device__ __forceinline__ float dppf(float v) {
    return __int_as_float(__builtin_amdgcn_update_dpp(
        __float_as_int(v), __float_as_int(v), CTRL, 0xF, 0xF, true));
}
constexpr int BC1 = 0x55;  // quad broadcast lane1 -> f
constexpr int BC2 = 0xAA;  // quad broadcast lane2 -> g
constexpr int BC3 = 0xFF;  // quad broadcast lane3 -> o

__device__ __forceinline__ float tanh_(float c) {
    // tanh(c) = 2/(1+2^(-2*log2e*c)) - 1
    return fmaf(2.0f, rcp_(1.0f + exp2_(-2.0f * LOG2E * c)), -1.0f);
}
} // namespace

__global__
__attribute__((amdgpu_flat_work_group_size(256, 256)))
__attribute__((amdgpu_waves_per_eu(4, 4)))
void lstm2_fc_kernel(
    const float* __restrict__ x,      // (4096, 512, 2)
    const float* __restrict__ W_ih0,  // (48, 2)
    const float* __restrict__ W_hh0,  // (48, 12)
    const float* __restrict__ b_ih0,  // (48)
    const float* __restrict__ b_hh0,  // (48)
    const float* __restrict__ W_ih1,  // (48, 12)
    const float* __restrict__ W_hh1,  // (48, 12)
    const float* __restrict__ b_ih1,  // (48)
    const float* __restrict__ b_hh1,  // (48)
    const float* __restrict__ fc_W,   // (2, 12)
    const float* __restrict__ fc_b,   // (2)
    float* __restrict__ out)          // (4096, 2)
{
    const int lane = threadIdx.x & 63;
    const int wid  = __builtin_amdgcn_readfirstlane((int)threadIdx.x >> 6);
    const int b    = blockIdx.x * 4 + wid;       // one element per wave
    const int u    = lane >> 2;                  // unit 0..15 (12 active)
    const int gate = lane & 3;                   // 0:i 1:f 2:g 3:o
    const int uc   = (u < H) ? u : 0;            // clamp idle lanes
    const int r    = gate * H + uc;              // weight row

    // sigmoid for i,f,o; tanh (=2*sigm(2x)-1) for g; exp2 prescale kmul
    // folded into weights & bias.
    const float pre  = (gate == 2) ? 2.0f : 1.0f;
    const float kmul = -LOG2E * pre;
    const float pa   = 1.0f - pre;

    // ---- per-wave private LDS: only h1 (12 floats + pad) ----
    __shared__ float sm[4 * 16];
    float* smb = &sm[wid * 16];
    const bool writer = (gate == 0) && (u < H);  // banks 0-11, conflict-free
    float* smw = smb + uc;

    // ---------------- prescaled packed weights -> registers ----------------
    f2 wx, whh0p[6], wih1p[6], whh1p[6];
    wx.x = kmul * W_ih0[r * 2 + 0];
    wx.y = kmul * W_ih0[r * 2 + 1];
#pragma unroll
    for (int k = 0; k < 6; ++k) {
        whh0p[k].x = kmul * W_hh0[r * H + 2 * k];
        whh0p[k].y = kmul * W_hh0[r * H + 2 * k + 1];
        wih1p[k].x = kmul * W_ih1[r * H + 2 * k];
        wih1p[k].y = kmul * W_ih1[r * H + 2 * k + 1];
        whh1p[k].x = kmul * W_hh1[r * H + 2 * k];
        whh1p[k].y = kmul * W_hh1[r * H + 2 * k + 1];
    }
    f2 bias0p, bias1p;
    bias0p.x = kmul * (b_ih0[r] + b_hh0[r]); bias0p.y = 0.0f;
    bias1p.x = kmul * (b_ih1[r] + b_hh1[r]); bias1p.y = 0.0f;

    // ---------------- state ----------------
    float c0 = 0.0f, c1 = 0.0f;
    f2 h0p[6], h1p[6];                            // h0(t) / h1(t-1) pairs
#pragma unroll
    for (int k = 0; k < 6; ++k) { h0p[k] = (f2)(0.0f); h1p[k] = (f2)(0.0f); }

    const float* xp = x + (size_t)b * T * 2;
    float2 xc = *(const float2*)xp;

    for (int t = 0; t < T; ++t) {
        const int tn = (t < T - 1) ? (t + 1) : t;
        const float2 xn = *(const float2*)(xp + 2 * tn);   // prefetch

        // ---- layer-0 dot (3 chains, prescaled by kmul) ----
        f2 xv; xv.x = xc.x; xv.y = xc.y;
        f2 cA = fma2(wx, xv, bias0p);
        cA = fma2(whh0p[0], h0p[0], cA);
        cA = fma2(whh0p[1], h0p[1], cA);
        f2 cB = whh0p[2] * h0p[2];
        cB = fma2(whh0p[3], h0p[3], cB);
        f2 cC = whh0p[4] * h0p[4];
        cC = fma2(whh0p[5], h0p[5], cC);
        cA = cA + cB + cC;
        const float s0 = fmaf(pre, rcp_(1.0f + exp2_(cA.x + cA.y)), pa);
        const float F0 = dppf<BC1>(s0);
        const float G0 = dppf<BC2>(s0);
        const float O0 = dppf<BC3>(s0);
        c0 = fmaf(F0, c0, s0 * G0);               // valid on gate-0 lanes
        const float h0v = O0 * tanh_(c0);         // h0(t) on lanes 4u

        // ---- layer-1 h1-part chains (independent of h0v; absorb bperm lat) --
        f2 dA = fma2(whh1p[0], h1p[0], bias1p);
        dA = fma2(whh1p[1], h1p[1], dA);
        f2 dB = whh1p[2] * h1p[2];
        dB = fma2(whh1p[3], h1p[3], dB);
        f2 dC = whh1p[4] * h1p[4];
        dC = fma2(whh1p[5], h1p[5], dC);

        // ---- h0 broadcast: 12 register-crossbar bpermutes (no round trip) --
        h0p[0].x = bperm_(0,   h0v);  h0p[0].y = bperm_(16,  h0v);
        h0p[1].x = bperm_(32,  h0v);  h0p[1].y = bperm_(48,  h0v);
        h0p[2].x = bperm_(64,  h0v);  h0p[2].y = bperm_(80,  h0v);
        h0p[3].x = bperm_(96,  h0v);  h0p[3].y = bperm_(112, h0v);
        h0p[4].x = bperm_(128, h0v);  h0p[4].y = bperm_(144, h0v);
        h0p[5].x = bperm_(160, h0v);  h0p[5].y = bperm_(176, h0v);

        // ---- layer-1 h0-part ----
        dA = fma2(wih1p[0], h0p[0], dA);
        dA = fma2(wih1p[1], h0p[1], dA);
        dB = fma2(wih1p[2], h0p[2], dB);
        dB = fma2(wih1p[3], h0p[3], dB);
        dC = fma2(wih1p[4], h0p[4], dC);
        dC = fma2(wih1p[5], h0p[5], dC);
        dA = dA + dB + dC;
        const float s1 = fmaf(pre, rcp_(1.0f + exp2_(dA.x + dA.y)), pa);
        const float F1 = dppf<BC1>(s1);
        const float G1 = dppf<BC2>(s1);
        const float O1 = dppf<BC3>(s1);
        c1 = fmaf(F1, c1, s1 * G1);               // c1(t) on gate-0 lanes
        const float h1v = O1 * tanh_(c1);         // h1(t)

        // ---- h1 publish via LDS: a full step of slack hides the latency ----
        if (writer) *smw = h1v;
        memfence_();
#pragma unroll
        for (int k = 0; k < 6; ++k) h1p[k] = *(const f2*)(smb + 2 * k);

        xc = xn;
    }

    // ---------------- final FC (lane 0; h1p holds h1(T-1) pairs) ------------
    if (lane == 0) {
        float r0 = fc_b[0];
        float r1 = fc_b[1];
#pragma unroll
        for (int k = 0; k < 6; ++k) {
            r0 = fmaf(fc_W[2 * k],     h1p[k].x, r0);
            r0 = fmaf(fc_W[2 * k + 1], h1p[k].y, r0);
            r1 = fmaf(fc_W[H + 2 * k],     h1p[k].x, r1);
            r1 = fmaf(fc_W[H + 2 * k + 1], h1p[k].y, r1);
        }
        float2 res; res.x = r0; res.y = r1;
        *(float2*)(out + (size_t)b * 2) = res;
    }
}

extern "C" void kernel_launch(void* const* d_in, const int* in_sizes, int n_in,
                              void* d_out, int out_size, void* d_ws, size_t ws_size,
                              hipStream_t stream) {
    const float* x     = (const float*)d_in[0];
    const float* W_ih0 = (const float*)d_in[1];
    const float* W_hh0 = (const float*)d_in[2];
    const float* b_ih0 = (const float*)d_in[3];
    const float* b_hh0 = (const float*)d_in[4];
    const float* W_ih1 = (const float*)d_in[5];
    const float* W_hh1 = (const float*)d_in[6];
    const float* b_ih1 = (const float*)d_in[7];
    const float* b_hh1 = (const float*)d_in[8];
    const float* fc_W  = (const float*)d_in[9];
    const float* fc_b  = (const float*)d_in[10];
    float* out = (float*)d_out;

    // 4096 elements, 1 per wave, 4 waves per block -> 1024 blocks
    lstm2_fc_kernel<<<1024, 256, 0, stream>>>(
        x, W_ih0, W_hh0, b_ih0, b_hh0,
        W_ih1, W_hh1, b_ih1, b_hh1, fc_W, fc_b, out);
}

// Round 17
// 261.876 us; speedup vs baseline: 1.2617x; 1.2617x over previous
//
#include <hip/hip_runtime.h>

// LSTMModel: B=4096, T=512, IN=2, H=12, OUT=2, fp32.
// r17: r10's exact instruction mix, but L1 LAGGED ONE STEP in the same wave.
// Interval t: compute L0(t) [publish h0(t)], compute L1(t-1) [publish h1(t-1)],
// then read h0(t), h1(t-1) for the NEXT interval. Every LDS round-trip gets a
// full phase of slack (the L1 block + loop tail hides ds_read latency), so the
// one tight dependency that capped r10's fill at 77% is gone.
// One elem/wave, lane = (unit u = lane>>2, gate = lane&3), 4 waves/SIMD.
// Peel interval 0 (L0 only + zero h1 region); epilogue runs L1(T-1).

namespace {
constexpr int H = 12;
constexpr int T = 512;
constexpr float LOG2E = 1.4426950408889634f;

typedef float f2 __attribute__((ext_vector_type(2)));

__device__ __forceinline__ f2 fma2(f2 a, f2 b, f2 c) {
    return __builtin_elementwise_fma(a, b, c);
}
__device__ __forceinline__ float exp2_(float x) {
    float r; asm("v_exp_f32 %0, %1" : "=v"(r) : "v"(x)); return r;
}
__device__ __forceinline__ float rcp_(float x) { return __builtin_amdgcn_rcpf(x); }
__device__ __forceinline__ void memfence_() { asm volatile("" ::: "memory"); }

template <int CTRL>
__device__ __forceinline__ float dppf(float v) {
    return __int_as_float(__builtin_amdgcn_update_dpp(
        __float_as_int(v), __float_as_int(v), CTRL, 0xF, 0xF, true));
}
constexpr int BC1 = 0x55;  // quad broadcast lane1 -> f
constexpr int BC2 = 0xAA;  // quad broadcast lane2 -> g
constexpr int BC3 = 0xFF;  // quad broadcast lane3 -> o

__device__ __forceinline__ float tanh_(float c) {
    // tanh(c) = 2/(1+2^(-2*log2e*c)) - 1
    return fmaf(2.0f, rcp_(1.0f + exp2_(-2.0f * LOG2E * c)), -1.0f);
}
} // namespace

__global__ __launch_bounds__(256, 4) void lstm2_fc_kernel(
    const float* __restrict__ x,      // (4096, 512, 2)
    const float* __restrict__ W_ih0,  // (48, 2)
    const float* __restrict__ W_hh0,  // (48, 12)
    const float* __restrict__ b_ih0,  // (48)
    const float* __restrict__ b_hh0,  // (48)
    const float* __restrict__ W_ih1,  // (48, 12)
    const float* __restrict__ W_hh1,  // (48, 12)
    const float* __restrict__ b_ih1,  // (48)
    const float* __restrict__ b_hh1,  // (48)
    const float* __restrict__ fc_W,   // (2, 12)
    const float* __restrict__ fc_b,   // (2)
    float* __restrict__ out)          // (4096, 2)
{
    const int lane = threadIdx.x & 63;
    const int wid  = __builtin_amdgcn_readfirstlane((int)threadIdx.x >> 6);
    const int b    = blockIdx.x * 4 + wid;       // one element per wave
    const int u    = lane >> 2;                  // unit 0..15 (12 active)
    const int gate = lane & 3;                   // 0:i 1:f 2:g 3:o
    const int uc   = (u < H) ? u : 0;            // clamp idle lanes
    const int r    = gate * H + uc;              // weight row

    // sigmoid for i,f,o; tanh (=2*sigm(2x)-1) for g; exp2 prescale kmul
    // folded into weights & bias.
    const float pre  = (gate == 2) ? 2.0f : 1.0f;
    const float kmul = -LOG2E * pre;
    const float pa   = 1.0f - pre;

    // ---- per-wave private LDS: h0 at [0..11], h1 at [16..27] ----
    __shared__ float sm[4 * 32];
    float* smb = &sm[wid * 32];
    const bool writer = (gate == 0) && (u < H);  // banks 0-11 / 16-27
    float* smw0 = smb + uc;
    float* smw1 = smb + 16 + uc;

    // ---------------- prescaled packed weights -> registers ----------------
    f2 wx, whh0p[6], wih1p[6], whh1p[6];
    wx.x = kmul * W_ih0[r * 2 + 0];
    wx.y = kmul * W_ih0[r * 2 + 1];
#pragma unroll
    for (int k = 0; k < 6; ++k) {
        whh0p[k].x = kmul * W_hh0[r * H + 2 * k];
        whh0p[k].y = kmul * W_hh0[r * H + 2 * k + 1];
        wih1p[k].x = kmul * W_ih1[r * H + 2 * k];
        wih1p[k].y = kmul * W_ih1[r * H + 2 * k + 1];
        whh1p[k].x = kmul * W_hh1[r * H + 2 * k];
        whh1p[k].y = kmul * W_hh1[r * H + 2 * k + 1];
    }
    f2 bias0p, bias1p;
    bias0p.x = kmul * (b_ih0[r] + b_hh0[r]); bias0p.y = 0.0f;
    bias1p.x = kmul * (b_ih1[r] + b_hh1[r]); bias1p.y = 0.0f;

    // ---------------- state ----------------
    float c0 = 0.0f, c1 = 0.0f;
    f2 hp0[6], hq1[6];                 // h0(t-1) and h1(t-2) at interval t
#pragma unroll
    for (int k = 0; k < 6; ++k) { hp0[k] = (f2)(0.0f); hq1[k] = (f2)(0.0f); }

    const float* xp = x + (size_t)b * T * 2;
    float2 xc = *(const float2*)xp;              // x(0)

    // ---- peel interval 0: L0 step 0 (h0(-1)=0 -> skip h-FMAs), zero h1 ----
    {
        f2 xv; xv.x = xc.x; xv.y = xc.y;
        f2 cA = fma2(wx, xv, bias0p);
        const float s0 = fmaf(pre, rcp_(1.0f + exp2_(cA.x + cA.y)), pa);
        const float F0 = dppf<BC1>(s0);
        const float G0 = dppf<BC2>(s0);
        const float O0 = dppf<BC3>(s0);
        (void)F0;
        c0 = s0 * G0;                            // f*0 + i*g
        const float h0v = O0 * tanh_(c0);
        if (writer) { *smw0 = h0v; *smw1 = 0.0f; }
        memfence_();
        // preload for interval 1: h0(0), h1(-1)=0
#pragma unroll
        for (int k = 0; k < 6; ++k) hp0[k] = *(const f2*)(smb + 2 * k);
#pragma unroll
        for (int k = 0; k < 6; ++k) hq1[k] = *(const f2*)(smb + 16 + 2 * k);
        memfence_();
        xc = *(const float2*)(xp + 2);           // x(1)
    }

    for (int t = 1; t < T; ++t) {
        const int tn = (t < T - 1) ? (t + 1) : t;
        const float2 xn = *(const float2*)(xp + 2 * tn);   // prefetch

        // ---- L0 step t (hp0 = h0(t-1)) ----
        f2 xv; xv.x = xc.x; xv.y = xc.y;
        f2 cA = fma2(wx, xv, bias0p);
        cA = fma2(whh0p[0], hp0[0], cA);
        cA = fma2(whh0p[1], hp0[1], cA);
        f2 cB = whh0p[2] * hp0[2];
        cB = fma2(whh0p[3], hp0[3], cB);
        f2 cC = whh0p[4] * hp0[4];
        cC = fma2(whh0p[5], hp0[5], cC);
        cA = cA + cB + cC;
        const float s0 = fmaf(pre, rcp_(1.0f + exp2_(cA.x + cA.y)), pa);
        const float F0 = dppf<BC1>(s0);
        const float G0 = dppf<BC2>(s0);
        const float O0 = dppf<BC3>(s0);
        c0 = fmaf(F0, c0, s0 * G0);              // valid on gate-0 lanes
        const float h0v = O0 * tanh_(c0);
        if (writer) *smw0 = h0v;                 // publish h0(t)

        // ---- L1 step t-1 (hp0 = h0(t-1), hq1 = h1(t-2)) ----
        f2 dA = fma2(whh1p[0], hq1[0], bias1p);
        dA = fma2(wih1p[0], hp0[0], dA);
        dA = fma2(whh1p[1], hq1[1], dA);
        dA = fma2(wih1p[1], hp0[1], dA);
        f2 dB = whh1p[2] * hq1[2];
        dB = fma2(wih1p[2], hp0[2], dB);
        dB = fma2(whh1p[3], hq1[3], dB);
        dB = fma2(wih1p[3], hp0[3], dB);
        f2 dC = whh1p[4] * hq1[4];
        dC = fma2(wih1p[4], hp0[4], dC);
        dC = fma2(whh1p[5], hq1[5], dC);
        dC = fma2(wih1p[5], hp0[5], dC);
        dA = dA + dB + dC;
        const float s1 = fmaf(pre, rcp_(1.0f + exp2_(dA.x + dA.y)), pa);
        const float F1 = dppf<BC1>(s1);
        const float G1 = dppf<BC2>(s1);
        const float O1 = dppf<BC3>(s1);
        c1 = fmaf(F1, c1, s1 * G1);              // c1(t-1)
        const float h1v = O1 * tanh_(c1);
        if (writer) *smw1 = h1v;                 // publish h1(t-1)

        // ---- slack-loaded readbacks for the NEXT interval ----
        memfence_();
#pragma unroll
        for (int k = 0; k < 6; ++k) hp0[k] = *(const f2*)(smb + 2 * k);
#pragma unroll
        for (int k = 0; k < 6; ++k) hq1[k] = *(const f2*)(smb + 16 + 2 * k);
        memfence_();
        xc = xn;
    }

    // ---- epilogue: L1 step T-1 (hp0 = h0(T-1), hq1 = h1(T-2) in regs) ----
    {
        f2 dA = fma2(whh1p[0], hq1[0], bias1p);
        dA = fma2(wih1p[0], hp0[0], dA);
        dA = fma2(whh1p[1], hq1[1], dA);
        dA = fma2(wih1p[1], hp0[1], dA);
        f2 dB = whh1p[2] * hq1[2];
        dB = fma2(wih1p[2], hp0[2], dB);
        dB = fma2(whh1p[3], hq1[3], dB);
        dB = fma2(wih1p[3], hp0[3], dB);
        f2 dC = whh1p[4] * hq1[4];
        dC = fma2(wih1p[4], hp0[4], dC);
        dC = fma2(whh1p[5], hq1[5], dC);
        dC = fma2(wih1p[5], hp0[5], dC);
        dA = dA + dB + dC;
        const float s1 = fmaf(pre, rcp_(1.0f + exp2_(dA.x + dA.y)), pa);
        const float F1 = dppf<BC1>(s1);
        const float G1 = dppf<BC2>(s1);
        const float O1 = dppf<BC3>(s1);
        c1 = fmaf(F1, c1, s1 * G1);              // c1(T-1)
        const float h1v = O1 * tanh_(c1);
        if (writer) *smw1 = h1v;                 // publish h1(T-1)
        memfence_();
#pragma unroll
        for (int k = 0; k < 6; ++k) hq1[k] = *(const f2*)(smb + 16 + 2 * k);
    }

    // ---------------- final FC (lane 0; hq1 = h1(T-1) pairs) ----------------
    if (lane == 0) {
        float r0 = fc_b[0];
        float r1 = fc_b[1];
#pragma unroll
        for (int k = 0; k < 6; ++k) {
            r0 = fmaf(fc_W[2 * k],     hq1[k].x, r0);
            r0 = fmaf(fc_W[2 * k + 1], hq1[k].y, r0);
            r1 = fmaf(fc_W[H + 2 * k],     hq1[k].x, r1);
            r1 = fmaf(fc_W[H + 2 * k + 1], hq1[k].y, r1);
        }
        float2 res; res.x = r0; res.y = r1;
        *(float2*)(out + (size_t)b * 2) = res;
    }
}

extern "C" void kernel_launch(void* const* d_in, const int* in_sizes, int n_in,
                              void* d_out, int out_size, void* d_ws, size_t ws_size,
                              hipStream_t stream) {
    const float* x     = (const float*)d_in[0];
    const float* W_ih0 = (const float*)d_in[1];
    const float* W_hh0 = (const float*)d_in[2];
    const float* b_ih0 = (const float*)d_in[3];
    const float* b_hh0 = (const float*)d_in[4];
    const float* W_ih1 = (const float*)d_in[5];
    const float* W_hh1 = (const float*)d_in[6];
    const float* b_ih1 = (const float*)d_in[7];
    const float* b_hh1 = (const float*)d_in[8];
    const float* fc_W  = (const float*)d_in[9];
    const float* fc_b  = (const float*)d_in[10];
    float* out = (float*)d_out;

    // 4096 elements, 1 per wave, 4 waves per block -> 1024 blocks
    lstm2_fc_kernel<<<1024, 256, 0, stream>>>(
        x, W_ih0, W_hh0, b_ih0, b_hh0,
        W_ih1, W_hh1, b_ih1, b_hh1, fc_W, fc_b, out);
}